// Round 4
// baseline (22.479 us; speedup 1.0000x reference)
//
#include <hip/hip_runtime.h>
#include <math.h>

// B=128, N=512, D=1024, C=512
// s: (128,1536) f32, a=s[:,:512], z=s[:,512:]; out: (128,1536) f32 = [da | dz]
// GEMM1: da = tanh([a|ctx](128x1024) @ [Wa;Wc](1024x512) + ba)
// GEMM2: c  = a(128x512) @ Wl(512x1024) + bl
// dz[b,i] = sum_k c[b,k] * z[b,(i+k)%1024]
//
// k1: blocks [0,32)  = GEMM2 (direct-from-global fragments, B staged in LDS,
//                      M-split-8 waves -> no cross-wave reduce), c -> ws
//     blocks [32,48) = pack A ([a|ctx] 128x1024) to bf16 fragments in ws
// k2: blocks [0,32)  = GEMM1 (A from ws pack, B staged in LDS, tanh epilogue)
//     blocks [32,288)= dz (fp32 VALU rolling-window circular correlation)
//
// Fragment k-slot bijection sigma(kq,j): j<4 -> 4kq+j ; j>=4 -> 16+4kq+(j-4),
// applied identically to A and B (validated rounds 2-3).

typedef float f32x4 __attribute__((ext_vector_type(4)));
typedef __bf16 bf16x8 __attribute__((ext_vector_type(8)));

// ws layout: Apack @ 0 : 8mt x 32ks x 64l x 8 bf16 = 256 KB ; c @ 256KB : 512 KB
#define C_OFF_BYTES 262144

__device__ __forceinline__ bf16x8 pack2(float4 v0, float4 v1) {
    bf16x8 r;
    r[0] = (__bf16)v0.x; r[1] = (__bf16)v0.y; r[2] = (__bf16)v0.z; r[3] = (__bf16)v0.w;
    r[4] = (__bf16)v1.x; r[5] = (__bf16)v1.y; r[6] = (__bf16)v1.z; r[7] = (__bf16)v1.w;
    return r;
}

// ---------------------------------------------------------------------------
// k1: 48 blocks x 512 threads
// ---------------------------------------------------------------------------
__global__ __launch_bounds__(512) void k1(
    const float* __restrict__ s, const float* __restrict__ ctx,
    const float* __restrict__ Wl, const float* __restrict__ bl,
    unsigned short* __restrict__ ws16, float* __restrict__ c)
{
    __shared__ __align__(16) unsigned short Bl[16 * 2 * 64 * 8];   // 32 KB

    const int bid = blockIdx.x;
    const int t = threadIdx.x;

    if (bid < 32) {
        // ---------------- GEMM2: c = a @ Wl + bl, cols [32*bid, 32*bid+32)
        const int N0 = bid * 32;
        const int w = t >> 6, l = t & 63;
        const int lk = l & 15, kq = l >> 4;

        // stage B frags for ks = 2w, 2w+1 (both nf)
        #pragma unroll
        for (int i = 0; i < 2; ++i) {
            const int ks = 2 * w + i;
            const int kb = ks * 32;
            #pragma unroll
            for (int nf = 0; nf < 2; ++nf) {
                const int col = N0 + 16 * nf + lk;
                bf16x8 fr;
                #pragma unroll
                for (int j = 0; j < 4; ++j)
                    fr[j] = (__bf16)Wl[(size_t)(kb + 4 * kq + j) * 1024 + col];
                #pragma unroll
                for (int j = 0; j < 4; ++j)
                    fr[4 + j] = (__bf16)Wl[(size_t)(kb + 16 + 4 * kq + j) * 1024 + col];
                *reinterpret_cast<uint4*>(&Bl[((ks * 2 + nf) * 64 + l) * 8]) =
                    __builtin_bit_cast(uint4, fr);
            }
        }
        __syncthreads();

        // compute: wave w owns rows 16w..16w+15, full K=512
        const float* arow = s + (size_t)(16 * w + lk) * 1536;
        f32x4 acc[2][2];
        #pragma unroll
        for (int p = 0; p < 2; ++p)
            #pragma unroll
            for (int nf = 0; nf < 2; ++nf)
                acc[p][nf] = (f32x4){0.f, 0.f, 0.f, 0.f};

        #pragma unroll 4
        for (int ks = 0; ks < 16; ++ks) {
            const int kb = ks * 32;
            float4 v0 = *reinterpret_cast<const float4*>(arow + kb + 4 * kq);
            float4 v1 = *reinterpret_cast<const float4*>(arow + kb + 16 + 4 * kq);
            bf16x8 af = pack2(v0, v1);
            uint4 b0 = *reinterpret_cast<const uint4*>(&Bl[((ks * 2 + 0) * 64 + l) * 8]);
            uint4 b1 = *reinterpret_cast<const uint4*>(&Bl[((ks * 2 + 1) * 64 + l) * 8]);
            const int p = ks & 1;
            acc[p][0] = __builtin_amdgcn_mfma_f32_16x16x32_bf16(af, __builtin_bit_cast(bf16x8, b0), acc[p][0], 0, 0, 0);
            acc[p][1] = __builtin_amdgcn_mfma_f32_16x16x32_bf16(af, __builtin_bit_cast(bf16x8, b1), acc[p][1], 0, 0, 0);
        }

        // epilogue: D map col=lk, row=4kq+r (within 16-row frag)
        #pragma unroll
        for (int nf = 0; nf < 2; ++nf) {
            f32x4 sum = acc[0][nf] + acc[1][nf];
            const int col = N0 + 16 * nf + lk;
            const float bias = bl[col];
            #pragma unroll
            for (int r = 0; r < 4; ++r)
                c[(size_t)(16 * w + 4 * kq + r) * 1024 + col] = sum[r] + bias;
        }
    } else {
        // ---------------- A pack: [a|ctx] -> bf16 frags, 16384 lane-frags
        const int base = (bid - 32) * 512 + t;
        #pragma unroll
        for (int rep = 0; rep < 2; ++rep) {
            const int idx = base + rep * 8192;
            const int mt = idx >> 11, ks = (idx >> 6) & 31, l2 = idx & 63;
            const int lk2 = l2 & 15, kq2 = l2 >> 4;
            const int row = 16 * mt + lk2, kb = 32 * ks;
            float4 v0, v1;
            if (ks < 16) {
                v0 = *reinterpret_cast<const float4*>(s + (size_t)row * 1536 + kb + 4 * kq2);
                v1 = *reinterpret_cast<const float4*>(s + (size_t)row * 1536 + kb + 16 + 4 * kq2);
            } else {
                v0 = *reinterpret_cast<const float4*>(ctx + (size_t)row * 512 + (kb - 512) + 4 * kq2);
                v1 = *reinterpret_cast<const float4*>(ctx + (size_t)row * 512 + (kb - 512) + 16 + 4 * kq2);
            }
            bf16x8 fr = pack2(v0, v1);
            *reinterpret_cast<uint4*>(ws16 + (size_t)idx * 8) = __builtin_bit_cast(uint4, fr);
        }
    }
}

// ---------------------------------------------------------------------------
// k2: 288 blocks x 512 threads (blocks [0,32)=GEMM1, [32,288)=dz)
// ---------------------------------------------------------------------------
__global__ __launch_bounds__(512) void k2(
    const float* __restrict__ s,
    const float* __restrict__ Wa, const float* __restrict__ Wc,
    const float* __restrict__ ba,
    const unsigned short* __restrict__ apack, const float* __restrict__ c,
    float* __restrict__ out)
{
    __shared__ __align__(16) unsigned char smem[32768];

    const int bid = blockIdx.x;
    const int t = threadIdx.x;

    if (bid < 32) {
        // ---------------- GEMM1: da = tanh([a|ctx] @ [Wa;Wc] + ba), 16 cols
        unsigned short* Bg = reinterpret_cast<unsigned short*>(smem);  // [32ks][64l][8]
        const int N0 = bid * 16;
        const int w = t >> 6, l = t & 63;
        const int lk = l & 15, kq = l >> 4;

        // stage B frags for ks = 4w..4w+3
        #pragma unroll
        for (int i = 0; i < 4; ++i) {
            const int ks = 4 * w + i;
            const int kb = ks * 32;
            const float* wb;
            int krel;
            if (ks < 16) { wb = Wa; krel = kb; }
            else         { wb = Wc; krel = kb - 512; }
            const int col = N0 + lk;
            bf16x8 fr;
            #pragma unroll
            for (int j = 0; j < 4; ++j)
                fr[j] = (__bf16)wb[(size_t)(krel + 4 * kq + j) * 512 + col];
            #pragma unroll
            for (int j = 0; j < 4; ++j)
                fr[4 + j] = (__bf16)wb[(size_t)(krel + 16 + 4 * kq + j) * 512 + col];
            *reinterpret_cast<uint4*>(&Bg[(ks * 64 + l) * 8]) = __builtin_bit_cast(uint4, fr);
        }
        __syncthreads();

        // compute: wave w owns rows 16w..16w+15 (mt=w), full K=1024
        const unsigned short* ap = apack + ((size_t)w * 32 * 64 + l) * 8;
        f32x4 acc[4];
        #pragma unroll
        for (int p = 0; p < 4; ++p) acc[p] = (f32x4){0.f, 0.f, 0.f, 0.f};

        #pragma unroll 8
        for (int ks = 0; ks < 32; ++ks) {
            uint4 av = *reinterpret_cast<const uint4*>(ap + (size_t)ks * 64 * 8);
            uint4 bv = *reinterpret_cast<const uint4*>(&Bg[(ks * 64 + l) * 8]);
            acc[ks & 3] = __builtin_amdgcn_mfma_f32_16x16x32_bf16(
                __builtin_bit_cast(bf16x8, av), __builtin_bit_cast(bf16x8, bv), acc[ks & 3], 0, 0, 0);
        }

        f32x4 sum = (acc[0] + acc[1]) + (acc[2] + acc[3]);
        const int col = N0 + lk;
        const float bias = ba[col];
        #pragma unroll
        for (int r = 0; r < 4; ++r)
            out[(size_t)(16 * w + 4 * kq + r) * 1536 + col] = tanhf(sum[r] + bias);
    } else {
        // ---------------- dz: (batch, i-half) per block, validated round 3
        float* zdup = reinterpret_cast<float*>(smem);            // 2064 f
        float* part = reinterpret_cast<float*>(smem + 8256);     // 8*512 f
        const int bz = bid - 32;
        const int b = bz >> 1;
        const int ih = bz & 1;
        if (t < 256) {
            float4 v = reinterpret_cast<const float4*>(s + (size_t)b * 1536 + 512)[t];
            reinterpret_cast<float4*>(zdup)[t] = v;
            reinterpret_cast<float4*>(zdup)[256 + t] = v;
        }
        __syncthreads();
        const int g = t & 63;
        const int kq = __builtin_amdgcn_readfirstlane(t >> 6);
        const float4* c4 = reinterpret_cast<const float4*>(c + (size_t)b * 1024 + kq * 128);
        const int I0 = ih * 512;
        const float4* z4 = reinterpret_cast<const float4*>(zdup);
        const int baseA = (I0 >> 2) + g + kq * 32;
        const int baseB = baseA + 64;
        float4 a0 = z4[baseA], a1 = z4[baseA + 1];
        float4 b0 = z4[baseB], b1 = z4[baseB + 1];
        float accA[4] = {0.f, 0.f, 0.f, 0.f}, accB[4] = {0.f, 0.f, 0.f, 0.f};
        #pragma unroll 4
        for (int m = 0; m < 32; ++m) {
            float4 cv = c4[m];
            float4 a2 = z4[baseA + m + 2];
            float4 b2 = z4[baseB + m + 2];
            accA[0] = fmaf(cv.x, a0.x, accA[0]); accA[0] = fmaf(cv.y, a0.y, accA[0]);
            accA[0] = fmaf(cv.z, a0.z, accA[0]); accA[0] = fmaf(cv.w, a0.w, accA[0]);
            accA[1] = fmaf(cv.x, a0.y, accA[1]); accA[1] = fmaf(cv.y, a0.z, accA[1]);
            accA[1] = fmaf(cv.z, a0.w, accA[1]); accA[1] = fmaf(cv.w, a1.x, accA[1]);
            accA[2] = fmaf(cv.x, a0.z, accA[2]); accA[2] = fmaf(cv.y, a0.w, accA[2]);
            accA[2] = fmaf(cv.z, a1.x, accA[2]); accA[2] = fmaf(cv.w, a1.y, accA[2]);
            accA[3] = fmaf(cv.x, a0.w, accA[3]); accA[3] = fmaf(cv.y, a1.x, accA[3]);
            accA[3] = fmaf(cv.z, a1.y, accA[3]); accA[3] = fmaf(cv.w, a1.z, accA[3]);
            accB[0] = fmaf(cv.x, b0.x, accB[0]); accB[0] = fmaf(cv.y, b0.y, accB[0]);
            accB[0] = fmaf(cv.z, b0.z, accB[0]); accB[0] = fmaf(cv.w, b0.w, accB[0]);
            accB[1] = fmaf(cv.x, b0.y, accB[1]); accB[1] = fmaf(cv.y, b0.z, accB[1]);
            accB[1] = fmaf(cv.z, b0.w, accB[1]); accB[1] = fmaf(cv.w, b1.x, accB[1]);
            accB[2] = fmaf(cv.x, b0.z, accB[2]); accB[2] = fmaf(cv.y, b0.w, accB[2]);
            accB[2] = fmaf(cv.z, b1.x, accB[2]); accB[2] = fmaf(cv.w, b1.y, accB[2]);
            accB[3] = fmaf(cv.x, b0.w, accB[3]); accB[3] = fmaf(cv.y, b1.x, accB[3]);
            accB[3] = fmaf(cv.z, b1.y, accB[3]); accB[3] = fmaf(cv.w, b1.z, accB[3]);
            a0 = a1; a1 = a2; b0 = b1; b1 = b2;
        }
        *reinterpret_cast<float4*>(&part[kq * 512 + 4 * g]) = make_float4(accA[0], accA[1], accA[2], accA[3]);
        *reinterpret_cast<float4*>(&part[kq * 512 + 256 + 4 * g]) = make_float4(accB[0], accB[1], accB[2], accB[3]);
        __syncthreads();
        float sum = 0.f;
        #pragma unroll
        for (int q = 0; q < 8; ++q) sum += part[q * 512 + t];
        out[(size_t)b * 1536 + 512 + I0 + t] = sum;
    }
}

extern "C" void kernel_launch(void* const* d_in, const int* in_sizes, int n_in,
                              void* d_out, int out_size, void* d_ws, size_t ws_size,
                              hipStream_t stream) {
    // inputs: 0=t, 1=s, 2=context, 3=Wa, 4=Wc, 5=ba, 6=Wl, 7=bl
    const float* s   = (const float*)d_in[1];
    const float* ctx = (const float*)d_in[2];
    const float* Wa  = (const float*)d_in[3];
    const float* Wc  = (const float*)d_in[4];
    const float* ba  = (const float*)d_in[5];
    const float* Wl  = (const float*)d_in[6];
    const float* bl  = (const float*)d_in[7];
    float* out = (float*)d_out;

    unsigned short* ws16 = (unsigned short*)d_ws;
    float* c = (float*)((char*)d_ws + C_OFF_BYTES);

    k1<<<48, 512, 0, stream>>>(s, ctx, Wl, bl, ws16, c);
    k2<<<288, 512, 0, stream>>>(s, Wa, Wc, ba, ws16, c, out);
}